// Round 5
// baseline (222.991 us; speedup 1.0000x reference)
//
#include <hip/hip_runtime.h>
#include <hip/hip_bf16.h>

#define CIN  128
#define FOUT 128
#define HID  32
#define EPSV 1e-8f

typedef __attribute__((ext_vector_type(8))) short bf16x8;
typedef __attribute__((ext_vector_type(4))) float f32x4;

__device__ inline short f2bf(float x) {
    union { float f; unsigned u; } v; v.f = x;
    unsigned r = v.u + 0x7fffu + ((v.u >> 16) & 1u);
    return (short)(r >> 16);
}
__device__ inline float bfbits2f(unsigned b) {
    union { unsigned u; float f; } v; v.u = b << 16;
    return v.f;
}

// ---------------------------------------------------------------------------
// Prep: WcT/W1T bf16 transposes, padded verts [N][4], zero counts.
// ---------------------------------------------------------------------------
__global__ void prep_kernel(const float* __restrict__ Wc,
                            const float* __restrict__ W1,
                            const float* __restrict__ verts,
                            short* __restrict__ WcT,
                            short* __restrict__ W1T,
                            float* __restrict__ vertsP,
                            int* __restrict__ counts,
                            int N) {
    const int idx = blockIdx.x * 256 + threadIdx.x;
    if (idx < CIN * FOUT) {
        const int c = idx >> 7, k = idx & 127;
        WcT[c * CIN + k] = f2bf(Wc[k * FOUT + c]);
    }
    if (idx < HID * CIN) {
        const int c = idx >> 7, k = idx & 127;
        W1T[c * CIN + k] = f2bf(W1[k * HID + c]);
    }
    if (idx < N) {
        vertsP[idx * 4 + 0] = verts[idx * 3 + 0];
        vertsP[idx * 4 + 1] = verts[idx * 3 + 1];
        vertsP[idx * 4 + 2] = verts[idx * 3 + 2];
        vertsP[idx * 4 + 3] = 0.f;
        counts[idx] = 0;
    }
}

// ---------------------------------------------------------------------------
// Per-16-vertex wave: MFMA xw = feat@Wc (bf16), h = relu(feat@W1+b1),
// then M = h@W2+b2 and packed symmetric G = M^T M (6 vals, stride 8).
// xw tile staged in LDS -> coalesced dword row stores.
// ---------------------------------------------------------------------------
__global__ __launch_bounds__(256) void vertex_mfma(
    const float* __restrict__ feat,
    const short* __restrict__ WcT,    // [FOUT][CIN] bf16
    const short* __restrict__ W1T,    // [HID][CIN] bf16
    const float* __restrict__ b1,
    const float* __restrict__ W2,     // [HID][9]
    const float* __restrict__ b2,
    float* __restrict__ Gp,           // [N][8] packed symmetric
    unsigned short* __restrict__ xwb, // [N][FOUT] bf16 bits
    int N) {
    __shared__ unsigned short xw_s[4][16][FOUT];
    __shared__ float h_lds[4][16][HID];
    __shared__ float M_lds[4][16][9];
    const int wid  = threadIdx.x >> 6;
    const int lane = threadIdx.x & 63;
    const int v0   = (blockIdx.x * 4 + wid) * 16;
    const int r    = lane & 15;
    const int hi   = lane >> 4;
    const int vr   = min(v0 + r, N - 1);

    // A fragments: 4 k-tiles of 32; lane holds feat[vr][kt*32 + hi*8 .. +8]
    bf16x8 a[4];
#pragma unroll
    for (int kt = 0; kt < 4; ++kt) {
        const float* src = feat + (size_t)vr * CIN + kt * 32 + hi * 8;
        const float4 f0 = ((const float4*)src)[0];
        const float4 f1 = ((const float4*)src)[1];
        bf16x8 t;
        t[0] = f2bf(f0.x); t[1] = f2bf(f0.y); t[2] = f2bf(f0.z); t[3] = f2bf(f0.w);
        t[4] = f2bf(f1.x); t[5] = f2bf(f1.y); t[6] = f2bf(f1.z); t[7] = f2bf(f1.w);
        a[kt] = t;
    }

    // xw: 8 column tiles of 16 -> stage in LDS
#pragma unroll
    for (int ct = 0; ct < 8; ++ct) {
        f32x4 acc = {0.f, 0.f, 0.f, 0.f};
#pragma unroll
        for (int kt = 0; kt < 4; ++kt) {
            const bf16x8 b = *((const bf16x8*)(WcT + (size_t)(ct * 16 + r) * CIN + kt * 32 + hi * 8));
            acc = __builtin_amdgcn_mfma_f32_16x16x32_bf16(a[kt], b, acc, 0, 0, 0);
        }
#pragma unroll
        for (int reg = 0; reg < 4; ++reg)
            xw_s[wid][hi * 4 + reg][ct * 16 + r] = (unsigned short)f2bf(acc[reg]);
    }

    // coalesced store: one 256B row per wave-wide dword store (intra-wave,
    // compiler inserts the lgkmcnt wait)
#pragma unroll
    for (int row = 0; row < 16; ++row) {
        if (v0 + row < N) {
            const unsigned d = ((const unsigned*)xw_s[wid][row])[lane];
            ((unsigned*)(xwb + (size_t)(v0 + row) * FOUT))[lane] = d;
        }
    }

    // h: 2 column tiles of 16 over W1T
#pragma unroll
    for (int ct = 0; ct < 2; ++ct) {
        f32x4 acc = {0.f, 0.f, 0.f, 0.f};
#pragma unroll
        for (int kt = 0; kt < 4; ++kt) {
            const bf16x8 b = *((const bf16x8*)(W1T + (size_t)(ct * 16 + r) * CIN + kt * 32 + hi * 8));
            acc = __builtin_amdgcn_mfma_f32_16x16x32_bf16(a[kt], b, acc, 0, 0, 0);
        }
        const float bb = b1[ct * 16 + r];
#pragma unroll
        for (int reg = 0; reg < 4; ++reg)
            h_lds[wid][hi * 4 + reg][ct * 16 + r] = fmaxf(acc[reg] + bb, 0.f);
    }
    __syncthreads();

    // M = h @ W2 + b2  (16 verts x 9 outputs per wave)
    for (int idx = lane; idx < 144; idx += 64) {
        const int v = idx / 9, t = idx - v * 9;
        float m = b2[t];
#pragma unroll
        for (int k = 0; k < HID; ++k)
            m = fmaf(h_lds[wid][v][k], W2[k * 9 + t], m);
        M_lds[wid][v][t] = m;
    }
    __syncthreads();

    // Packed symmetric G: t in [0,6) -> (i,j) upper triangle
    for (int idx = lane; idx < 96; idx += 64) {
        const int v = idx / 6, t = idx - v * 6;
        const int i = (t >= 3) + (t >= 5);
        const int j = t - (t >= 3) * 2 - (t >= 5);
        float g = 0.f;
#pragma unroll
        for (int k = 0; k < 3; ++k)
            g += M_lds[wid][v][k * 3 + i] * M_lds[wid][v][k * 3 + j];
        if (v0 + v < N) Gp[(size_t)(v0 + v) * 8 + t] = g;
    }
}

// ---------------------------------------------------------------------------
// Histogram of src; records each edge's arrival rank within its bucket.
// ---------------------------------------------------------------------------
__global__ void hist_kernel(const int* __restrict__ edges, int* __restrict__ counts,
                            int* __restrict__ rank, int E) {
    const int e = blockIdx.x * blockDim.x + threadIdx.x;
    if (e < E) rank[e] = atomicAdd(&counts[edges[e]], 1);
}

// ---------------------------------------------------------------------------
// Single-block exclusive scan of counts -> offset (N up to 1024*chunk).
// ---------------------------------------------------------------------------
__global__ __launch_bounds__(1024) void scan_kernel(const int* __restrict__ counts,
                                                    int* __restrict__ offset, int N) {
    __shared__ int s[1024];
    const int t = threadIdx.x;
    const int chunk = (N + 1023) >> 10;
    const int lo = min(t * chunk, N);
    const int hi = min(lo + chunk, N);
    int sum = 0;
    for (int i = lo; i < hi; ++i) sum += counts[i];
    s[t] = sum;
    __syncthreads();
    for (int off = 1; off < 1024; off <<= 1) {
        int v = (t >= off) ? s[t - off] : 0;
        __syncthreads();
        s[t] += v;
        __syncthreads();
    }
    int run = s[t] - sum;   // exclusive prefix of this thread's chunk
    for (int i = lo; i < hi; ++i) {
        offset[i] = run;
        run += counts[i];
    }
}

// ---------------------------------------------------------------------------
// CSR fill: w = exp(-0.5 (t^T Gs t + t^T Gd t)); scatter packed (dst, w).
// ---------------------------------------------------------------------------
__global__ void fill_kernel(const int* __restrict__ edges,
                            const int* __restrict__ rank,
                            const int* __restrict__ offset,
                            const float* __restrict__ vertsP,  // [N][4]
                            const float* __restrict__ Gp,      // [N][8]
                            int2* __restrict__ dstw,
                            int E) {
    const int e = blockIdx.x * blockDim.x + threadIdx.x;
    if (e >= E) return;
    const int s = edges[e];
    const int d = edges[E + e];

    const float4 vs = ((const float4*)vertsP)[s];
    const float4 vd = ((const float4*)vertsP)[d];
    const float t0 = vd.x - vs.x, t1 = vd.y - vs.y, t2 = vd.z - vs.z;

    const float* gs = Gp + (size_t)s * 8;
    const float* gd = Gp + (size_t)d * 8;
    const float4 ga = ((const float4*)gs)[0];
    const float2 gb = ((const float2*)(gs + 4))[0];
    const float4 ha = ((const float4*)gd)[0];
    const float2 hb = ((const float2*)(gd + 4))[0];

    const float g00 = ga.x + ha.x, g01 = ga.y + ha.y, g02 = ga.z + ha.z;
    const float g11 = ga.w + ha.w, g12 = gb.x + hb.x, g22 = gb.y + hb.y;

    const float q = 0.5f * (g00 * t0 * t0 + g11 * t1 * t1 + g22 * t2 * t2
                  + 2.f * (g01 * t0 * t1 + g02 * t0 * t2 + g12 * t1 * t2));
    const float w = expf(-q);

    const int slot = offset[s] + rank[e];
    dstw[slot] = make_int2(d, __float_as_int(w));
}

// ---------------------------------------------------------------------------
// Gather aggregation: one wave per vertex; lane l owns cols {2l, 2l+1}.
// ---------------------------------------------------------------------------
__global__ __launch_bounds__(256) void agg_kernel(const int* __restrict__ offset,
                                                  const int* __restrict__ counts,
                                                  const int2* __restrict__ dstw,
                                                  const unsigned short* __restrict__ xwb,
                                                  const float* __restrict__ bias,
                                                  float* __restrict__ out,
                                                  int N) {
    const int wid  = threadIdx.x >> 6;
    const int lane = threadIdx.x & 63;
    const int v = blockIdx.x * 4 + wid;
    if (v >= N) return;

    const int2* dw = dstw + offset[v];
    const int deg = counts[v];

    float ax = 0.f, ay = 0.f, wsum = 0.f;
    int k = 0;
    for (; k + 4 <= deg; k += 4) {
        const int2 p0 = dw[k];
        const int2 p1 = dw[k + 1];
        const int2 p2 = dw[k + 2];
        const int2 p3 = dw[k + 3];
        const unsigned u0 = ((const unsigned*)(xwb + (size_t)p0.x * FOUT))[lane];
        const unsigned u1 = ((const unsigned*)(xwb + (size_t)p1.x * FOUT))[lane];
        const unsigned u2 = ((const unsigned*)(xwb + (size_t)p2.x * FOUT))[lane];
        const unsigned u3 = ((const unsigned*)(xwb + (size_t)p3.x * FOUT))[lane];
        const float w0 = __int_as_float(p0.y), w1 = __int_as_float(p1.y);
        const float w2 = __int_as_float(p2.y), w3 = __int_as_float(p3.y);
        ax = fmaf(w0, bfbits2f(u0 & 0xffffu), ax); ay = fmaf(w0, bfbits2f(u0 >> 16), ay);
        ax = fmaf(w1, bfbits2f(u1 & 0xffffu), ax); ay = fmaf(w1, bfbits2f(u1 >> 16), ay);
        ax = fmaf(w2, bfbits2f(u2 & 0xffffu), ax); ay = fmaf(w2, bfbits2f(u2 >> 16), ay);
        ax = fmaf(w3, bfbits2f(u3 & 0xffffu), ax); ay = fmaf(w3, bfbits2f(u3 >> 16), ay);
        wsum += (w0 + w1) + (w2 + w3);
    }
    for (; k < deg; ++k) {
        const int2 p0 = dw[k];
        const unsigned u0 = ((const unsigned*)(xwb + (size_t)p0.x * FOUT))[lane];
        const float w0 = __int_as_float(p0.y);
        ax = fmaf(w0, bfbits2f(u0 & 0xffffu), ax);
        ay = fmaf(w0, bfbits2f(u0 >> 16), ay);
        wsum += w0;
    }

    const float inv = 1.f / (wsum + EPSV);
    const float2 b = ((const float2*)bias)[lane];
    float2 o;
    o.x = ax * inv + b.x;
    o.y = ay * inv + b.y;
    ((float2*)(out + (size_t)v * FOUT))[lane] = o;
}

extern "C" void kernel_launch(void* const* d_in, const int* in_sizes, int n_in,
                              void* d_out, int out_size, void* d_ws, size_t ws_size,
                              hipStream_t stream) {
    const float* feat  = (const float*)d_in[0];
    const float* verts = (const float*)d_in[1];
    const int*   edges = (const int*)d_in[2];
    // d_in[3] = faces (unused)
    const float* W1    = (const float*)d_in[4];
    const float* b1    = (const float*)d_in[5];
    const float* W2    = (const float*)d_in[6];
    const float* b2    = (const float*)d_in[7];
    const float* Wc    = (const float*)d_in[8];
    const float* bias  = (const float*)d_in[9];

    const int N = in_sizes[0] / CIN;
    const int E = in_sizes[2] / 2;

    // workspace layout (256B-aligned chunks)
    char* p = (char*)d_ws;
    auto alloc = [&](size_t bytes) {
        char* r = p;
        p += (bytes + 255) & ~(size_t)255;
        return r;
    };
    short*          WcT    = (short*)alloc((size_t)CIN * FOUT * sizeof(short));
    short*          W1T    = (short*)alloc((size_t)HID * CIN * sizeof(short));
    unsigned short* xwb    = (unsigned short*)alloc((size_t)N * FOUT * sizeof(short));
    float*          Gp     = (float*)alloc((size_t)N * 8 * sizeof(float));
    float*          vertsP = (float*)alloc((size_t)N * 4 * sizeof(float));
    int2*           dstw   = (int2*)alloc((size_t)E * sizeof(int2));
    int*            rank   = (int*)alloc((size_t)E * sizeof(int));
    int*            counts = (int*)alloc((size_t)N * sizeof(int));
    int*            offset = (int*)alloc((size_t)N * sizeof(int));
    float*          out    = (float*)d_out;

    const int prep_n = (N > CIN * FOUT) ? N : CIN * FOUT;
    prep_kernel<<<(prep_n + 255) / 256, 256, 0, stream>>>(Wc, W1, verts, WcT, W1T, vertsP, counts, N);

    const int nwaves = (N + 15) / 16;
    vertex_mfma<<<(nwaves + 3) / 4, 256, 0, stream>>>(feat, WcT, W1T, b1, W2, b2, Gp, xwb, N);

    hist_kernel<<<(E + 255) / 256, 256, 0, stream>>>(edges, counts, rank, E);
    scan_kernel<<<1, 1024, 0, stream>>>(counts, offset, N);
    fill_kernel<<<(E + 255) / 256, 256, 0, stream>>>(edges, rank, offset, vertsP, Gp, dstw, E);
    agg_kernel<<<(N + 3) / 4, 256, 0, stream>>>(offset, counts, dstw, xwb, bias, out, N);
}

// Round 6
// 153.696 us; speedup vs baseline: 1.4509x; 1.4509x over previous
//
#include <hip/hip_runtime.h>
#include <hip/hip_bf16.h>

#define CIN  128
#define FOUT 128
#define HID  32
#define EPSV 1e-8f

typedef __attribute__((ext_vector_type(8))) short bf16x8;
typedef __attribute__((ext_vector_type(4))) float f32x4;

__device__ inline short f2bf(float x) {
    union { float f; unsigned u; } v; v.f = x;
    unsigned r = v.u + 0x7fffu + ((v.u >> 16) & 1u);
    return (short)(r >> 16);
}
__device__ inline float bfbits2f(unsigned b) {
    union { unsigned u; float f; } v; v.u = b << 16;
    return v.f;
}

// ---------------------------------------------------------------------------
// Prep: WcT/W1T bf16 transposes, padded verts [N][4], zero counts + cursor.
// ---------------------------------------------------------------------------
__global__ void prep_kernel(const float* __restrict__ Wc,
                            const float* __restrict__ W1,
                            const float* __restrict__ verts,
                            short* __restrict__ WcT,
                            short* __restrict__ W1T,
                            float* __restrict__ vertsP,
                            int* __restrict__ counts,
                            int* __restrict__ cursor,
                            int N) {
    const int idx = blockIdx.x * 256 + threadIdx.x;
    if (idx == 0) *cursor = 0;
    if (idx < CIN * FOUT) {
        const int c = idx >> 7, k = idx & 127;
        WcT[c * CIN + k] = f2bf(Wc[k * FOUT + c]);
    }
    if (idx < HID * CIN) {
        const int c = idx >> 7, k = idx & 127;
        W1T[c * CIN + k] = f2bf(W1[k * HID + c]);
    }
    if (idx < N) {
        vertsP[idx * 4 + 0] = verts[idx * 3 + 0];
        vertsP[idx * 4 + 1] = verts[idx * 3 + 1];
        vertsP[idx * 4 + 2] = verts[idx * 3 + 2];
        vertsP[idx * 4 + 3] = 0.f;
        counts[idx] = 0;
    }
}

// ---------------------------------------------------------------------------
// Per-16-vertex wave: MFMA xw = feat@Wc (bf16), h = relu(feat@W1+b1),
// then M = h@W2+b2 and packed symmetric G = M^T M (6 vals, stride 8).
// xw tile staged in LDS -> coalesced dword row stores.
// ---------------------------------------------------------------------------
__global__ __launch_bounds__(256) void vertex_mfma(
    const float* __restrict__ feat,
    const short* __restrict__ WcT,    // [FOUT][CIN] bf16
    const short* __restrict__ W1T,    // [HID][CIN] bf16
    const float* __restrict__ b1,
    const float* __restrict__ W2,     // [HID][9]
    const float* __restrict__ b2,
    float* __restrict__ Gp,           // [N][8] packed symmetric
    unsigned short* __restrict__ xwb, // [N][FOUT] bf16 bits
    int N) {
    __shared__ unsigned short xw_s[4][16][FOUT];
    __shared__ float h_lds[4][16][HID];
    __shared__ float M_lds[4][16][9];
    const int wid  = threadIdx.x >> 6;
    const int lane = threadIdx.x & 63;
    const int v0   = (blockIdx.x * 4 + wid) * 16;
    const int r    = lane & 15;
    const int hi   = lane >> 4;
    const int vr   = min(v0 + r, N - 1);

    // A fragments: 4 k-tiles of 32; lane holds feat[vr][kt*32 + hi*8 .. +8]
    bf16x8 a[4];
#pragma unroll
    for (int kt = 0; kt < 4; ++kt) {
        const float* src = feat + (size_t)vr * CIN + kt * 32 + hi * 8;
        const float4 f0 = ((const float4*)src)[0];
        const float4 f1 = ((const float4*)src)[1];
        bf16x8 t;
        t[0] = f2bf(f0.x); t[1] = f2bf(f0.y); t[2] = f2bf(f0.z); t[3] = f2bf(f0.w);
        t[4] = f2bf(f1.x); t[5] = f2bf(f1.y); t[6] = f2bf(f1.z); t[7] = f2bf(f1.w);
        a[kt] = t;
    }

    // xw: 8 column tiles of 16 -> stage in LDS
#pragma unroll
    for (int ct = 0; ct < 8; ++ct) {
        f32x4 acc = {0.f, 0.f, 0.f, 0.f};
#pragma unroll
        for (int kt = 0; kt < 4; ++kt) {
            const bf16x8 b = *((const bf16x8*)(WcT + (size_t)(ct * 16 + r) * CIN + kt * 32 + hi * 8));
            acc = __builtin_amdgcn_mfma_f32_16x16x32_bf16(a[kt], b, acc, 0, 0, 0);
        }
#pragma unroll
        for (int reg = 0; reg < 4; ++reg)
            xw_s[wid][hi * 4 + reg][ct * 16 + r] = (unsigned short)f2bf(acc[reg]);
    }

    // coalesced store: one 256B row per wave-wide dword store
#pragma unroll
    for (int row = 0; row < 16; ++row) {
        if (v0 + row < N) {
            const unsigned d = ((const unsigned*)xw_s[wid][row])[lane];
            ((unsigned*)(xwb + (size_t)(v0 + row) * FOUT))[lane] = d;
        }
    }

    // h: 2 column tiles of 16 over W1T
#pragma unroll
    for (int ct = 0; ct < 2; ++ct) {
        f32x4 acc = {0.f, 0.f, 0.f, 0.f};
#pragma unroll
        for (int kt = 0; kt < 4; ++kt) {
            const bf16x8 b = *((const bf16x8*)(W1T + (size_t)(ct * 16 + r) * CIN + kt * 32 + hi * 8));
            acc = __builtin_amdgcn_mfma_f32_16x16x32_bf16(a[kt], b, acc, 0, 0, 0);
        }
        const float bb = b1[ct * 16 + r];
#pragma unroll
        for (int reg = 0; reg < 4; ++reg)
            h_lds[wid][hi * 4 + reg][ct * 16 + r] = fmaxf(acc[reg] + bb, 0.f);
    }
    __syncthreads();

    // M = h @ W2 + b2  (16 verts x 9 outputs per wave)
    for (int idx = lane; idx < 144; idx += 64) {
        const int v = idx / 9, t = idx - v * 9;
        float m = b2[t];
#pragma unroll
        for (int k = 0; k < HID; ++k)
            m = fmaf(h_lds[wid][v][k], W2[k * 9 + t], m);
        M_lds[wid][v][t] = m;
    }
    __syncthreads();

    // Packed symmetric G: t in [0,6) -> (i,j) upper triangle
    for (int idx = lane; idx < 96; idx += 64) {
        const int v = idx / 6, t = idx - v * 6;
        const int i = (t >= 3) + (t >= 5);
        const int j = t - (t >= 3) * 2 - (t >= 5);
        float g = 0.f;
#pragma unroll
        for (int k = 0; k < 3; ++k)
            g += M_lds[wid][v][k * 3 + i] * M_lds[wid][v][k * 3 + j];
        if (v0 + v < N) Gp[(size_t)(v0 + v) * 8 + t] = g;
    }
}

// ---------------------------------------------------------------------------
// Histogram of src; records each edge's arrival rank within its bucket.
// ---------------------------------------------------------------------------
__global__ void hist_kernel(const int* __restrict__ edges, int* __restrict__ counts,
                            int* __restrict__ rank, int E) {
    const int e = blockIdx.x * blockDim.x + threadIdx.x;
    if (e < E) rank[e] = atomicAdd(&counts[edges[e]], 1);
}

// ---------------------------------------------------------------------------
// Range allocation (replaces global scan): per-wave shfl scan of counts,
// block combines 4 wave totals, one atomicAdd on a global cursor per block.
// offset[v] ranges are disjoint+contiguous (order across blocks irrelevant).
// ---------------------------------------------------------------------------
__global__ __launch_bounds__(256) void offsets_kernel(const int* __restrict__ counts,
                                                      int* __restrict__ offset,
                                                      int* __restrict__ cursor, int N) {
    __shared__ int wtot[4];
    __shared__ int wbase[4];
    const int i = blockIdx.x * 256 + threadIdx.x;
    const int wid  = threadIdx.x >> 6;
    const int lane = threadIdx.x & 63;
    const int c = (i < N) ? counts[i] : 0;
    int s = c;
#pragma unroll
    for (int off = 1; off < 64; off <<= 1) {
        const int v = __shfl_up(s, off, 64);
        if (lane >= off) s += v;
    }
    if (lane == 63) wtot[wid] = s;
    __syncthreads();
    if (threadIdx.x == 0) {
        const int t0 = wtot[0], t1 = wtot[1], t2 = wtot[2], t3 = wtot[3];
        const int base = atomicAdd(cursor, t0 + t1 + t2 + t3);
        wbase[0] = base;
        wbase[1] = base + t0;
        wbase[2] = base + t0 + t1;
        wbase[3] = base + t0 + t1 + t2;
    }
    __syncthreads();
    if (i < N) offset[i] = wbase[wid] + s - c;
}

// ---------------------------------------------------------------------------
// CSR fill: w = exp(-0.5 (t^T Gs t + t^T Gd t)); scatter packed (dst, w).
// ---------------------------------------------------------------------------
__global__ void fill_kernel(const int* __restrict__ edges,
                            const int* __restrict__ rank,
                            const int* __restrict__ offset,
                            const float* __restrict__ vertsP,  // [N][4]
                            const float* __restrict__ Gp,      // [N][8]
                            int2* __restrict__ dstw,
                            int E) {
    const int e = blockIdx.x * blockDim.x + threadIdx.x;
    if (e >= E) return;
    const int s = edges[e];
    const int d = edges[E + e];

    const float4 vs = ((const float4*)vertsP)[s];
    const float4 vd = ((const float4*)vertsP)[d];
    const float t0 = vd.x - vs.x, t1 = vd.y - vs.y, t2 = vd.z - vs.z;

    const float* gs = Gp + (size_t)s * 8;
    const float* gd = Gp + (size_t)d * 8;
    const float4 ga = ((const float4*)gs)[0];
    const float2 gb = ((const float2*)(gs + 4))[0];
    const float4 ha = ((const float4*)gd)[0];
    const float2 hb = ((const float2*)(gd + 4))[0];

    const float g00 = ga.x + ha.x, g01 = ga.y + ha.y, g02 = ga.z + ha.z;
    const float g11 = ga.w + ha.w, g12 = gb.x + hb.x, g22 = gb.y + hb.y;

    const float q = 0.5f * (g00 * t0 * t0 + g11 * t1 * t1 + g22 * t2 * t2
                  + 2.f * (g01 * t0 * t1 + g02 * t0 * t2 + g12 * t1 * t2));
    const float w = expf(-q);

    const int slot = offset[s] + rank[e];
    dstw[slot] = make_int2(d, __float_as_int(w));
}

// ---------------------------------------------------------------------------
// Gather aggregation: one wave per vertex; lane l owns cols {2l, 2l+1}.
// ---------------------------------------------------------------------------
__global__ __launch_bounds__(256) void agg_kernel(const int* __restrict__ offset,
                                                  const int* __restrict__ counts,
                                                  const int2* __restrict__ dstw,
                                                  const unsigned short* __restrict__ xwb,
                                                  const float* __restrict__ bias,
                                                  float* __restrict__ out,
                                                  int N) {
    const int wid  = threadIdx.x >> 6;
    const int lane = threadIdx.x & 63;
    const int v = blockIdx.x * 4 + wid;
    if (v >= N) return;

    const int2* dw = dstw + offset[v];
    const int deg = counts[v];

    float ax = 0.f, ay = 0.f, wsum = 0.f;
    int k = 0;
    for (; k + 4 <= deg; k += 4) {
        const int2 p0 = dw[k];
        const int2 p1 = dw[k + 1];
        const int2 p2 = dw[k + 2];
        const int2 p3 = dw[k + 3];
        const unsigned u0 = ((const unsigned*)(xwb + (size_t)p0.x * FOUT))[lane];
        const unsigned u1 = ((const unsigned*)(xwb + (size_t)p1.x * FOUT))[lane];
        const unsigned u2 = ((const unsigned*)(xwb + (size_t)p2.x * FOUT))[lane];
        const unsigned u3 = ((const unsigned*)(xwb + (size_t)p3.x * FOUT))[lane];
        const float w0 = __int_as_float(p0.y), w1 = __int_as_float(p1.y);
        const float w2 = __int_as_float(p2.y), w3 = __int_as_float(p3.y);
        ax = fmaf(w0, bfbits2f(u0 & 0xffffu), ax); ay = fmaf(w0, bfbits2f(u0 >> 16), ay);
        ax = fmaf(w1, bfbits2f(u1 & 0xffffu), ax); ay = fmaf(w1, bfbits2f(u1 >> 16), ay);
        ax = fmaf(w2, bfbits2f(u2 & 0xffffu), ax); ay = fmaf(w2, bfbits2f(u2 >> 16), ay);
        ax = fmaf(w3, bfbits2f(u3 & 0xffffu), ax); ay = fmaf(w3, bfbits2f(u3 >> 16), ay);
        wsum += (w0 + w1) + (w2 + w3);
    }
    for (; k < deg; ++k) {
        const int2 p0 = dw[k];
        const unsigned u0 = ((const unsigned*)(xwb + (size_t)p0.x * FOUT))[lane];
        const float w0 = __int_as_float(p0.y);
        ax = fmaf(w0, bfbits2f(u0 & 0xffffu), ax);
        ay = fmaf(w0, bfbits2f(u0 >> 16), ay);
        wsum += w0;
    }

    const float inv = 1.f / (wsum + EPSV);
    const float2 b = ((const float2*)bias)[lane];
    float2 o;
    o.x = ax * inv + b.x;
    o.y = ay * inv + b.y;
    ((float2*)(out + (size_t)v * FOUT))[lane] = o;
}

extern "C" void kernel_launch(void* const* d_in, const int* in_sizes, int n_in,
                              void* d_out, int out_size, void* d_ws, size_t ws_size,
                              hipStream_t stream) {
    const float* feat  = (const float*)d_in[0];
    const float* verts = (const float*)d_in[1];
    const int*   edges = (const int*)d_in[2];
    // d_in[3] = faces (unused)
    const float* W1    = (const float*)d_in[4];
    const float* b1    = (const float*)d_in[5];
    const float* W2    = (const float*)d_in[6];
    const float* b2    = (const float*)d_in[7];
    const float* Wc    = (const float*)d_in[8];
    const float* bias  = (const float*)d_in[9];

    const int N = in_sizes[0] / CIN;
    const int E = in_sizes[2] / 2;

    // workspace layout (256B-aligned chunks)
    char* p = (char*)d_ws;
    auto alloc = [&](size_t bytes) {
        char* r = p;
        p += (bytes + 255) & ~(size_t)255;
        return r;
    };
    short*          WcT    = (short*)alloc((size_t)CIN * FOUT * sizeof(short));
    short*          W1T    = (short*)alloc((size_t)HID * CIN * sizeof(short));
    unsigned short* xwb    = (unsigned short*)alloc((size_t)N * FOUT * sizeof(short));
    float*          Gp     = (float*)alloc((size_t)N * 8 * sizeof(float));
    float*          vertsP = (float*)alloc((size_t)N * 4 * sizeof(float));
    int2*           dstw   = (int2*)alloc((size_t)E * sizeof(int2));
    int*            rank   = (int*)alloc((size_t)E * sizeof(int));
    int*            counts = (int*)alloc((size_t)N * sizeof(int));
    int*            offset = (int*)alloc((size_t)N * sizeof(int));
    int*            cursor = (int*)alloc(256);
    float*          out    = (float*)d_out;

    const int prep_n = (N > CIN * FOUT) ? N : CIN * FOUT;
    prep_kernel<<<(prep_n + 255) / 256, 256, 0, stream>>>(Wc, W1, verts, WcT, W1T, vertsP, counts, cursor, N);

    const int nwaves = (N + 15) / 16;
    vertex_mfma<<<(nwaves + 3) / 4, 256, 0, stream>>>(feat, WcT, W1T, b1, W2, b2, Gp, xwb, N);

    hist_kernel<<<(E + 255) / 256, 256, 0, stream>>>(edges, counts, rank, E);
    offsets_kernel<<<(N + 255) / 256, 256, 0, stream>>>(counts, offset, cursor, N);
    fill_kernel<<<(E + 255) / 256, 256, 0, stream>>>(edges, rank, offset, vertsP, Gp, dstw, E);
    agg_kernel<<<(N + 3) / 4, 256, 0, stream>>>(offset, counts, dstw, xwb, bias, out, N);
}

// Round 7
// 116.858 us; speedup vs baseline: 1.9082x; 1.3152x over previous
//
#include <hip/hip_runtime.h>
#include <hip/hip_bf16.h>

#define CIN  128
#define FOUT 128
#define HID  32
#define CAP  128
#define EPSV 1e-8f

typedef __attribute__((ext_vector_type(8))) short bf16x8;
typedef __attribute__((ext_vector_type(4))) float f32x4;

__device__ inline short f2bf(float x) {
    union { float f; unsigned u; } v; v.f = x;
    unsigned r = v.u + 0x7fffu + ((v.u >> 16) & 1u);
    return (short)(r >> 16);
}
__device__ inline float bfbits2f(unsigned b) {
    union { unsigned u; float f; } v; v.u = b << 16;
    return v.f;
}

// ---------------------------------------------------------------------------
// Prep: WcT/W1T bf16 transposes, padded verts [N][4], zero bucket cursors.
// ---------------------------------------------------------------------------
__global__ void prep_kernel(const float* __restrict__ Wc,
                            const float* __restrict__ W1,
                            const float* __restrict__ verts,
                            short* __restrict__ WcT,
                            short* __restrict__ W1T,
                            float* __restrict__ vertsP,
                            int* __restrict__ cur,
                            int N) {
    const int idx = blockIdx.x * 256 + threadIdx.x;
    if (idx < CIN * FOUT) {
        const int c = idx >> 7, k = idx & 127;
        WcT[c * CIN + k] = f2bf(Wc[k * FOUT + c]);
    }
    if (idx < HID * CIN) {
        const int c = idx >> 7, k = idx & 127;
        W1T[c * CIN + k] = f2bf(W1[k * HID + c]);
    }
    if (idx < N) {
        vertsP[idx * 4 + 0] = verts[idx * 3 + 0];
        vertsP[idx * 4 + 1] = verts[idx * 3 + 1];
        vertsP[idx * 4 + 2] = verts[idx * 3 + 2];
        vertsP[idx * 4 + 3] = 0.f;
        cur[idx] = 0;
    }
}

// ---------------------------------------------------------------------------
// Per-16-vertex wave: MFMA xw = feat@Wc (bf16), h = relu(feat@W1+b1),
// M = h@W2+b2, packed symmetric G = M^T M (6 vals, stride 8).
// Tail: grid-stride bucket-scatter of edges (independent of vertex phase,
// overlaps with other blocks' MFMA work).
// ---------------------------------------------------------------------------
__global__ __launch_bounds__(256) void vertex_mfma(
    const float* __restrict__ feat,
    const short* __restrict__ WcT,    // [FOUT][CIN] bf16
    const short* __restrict__ W1T,    // [HID][CIN] bf16
    const float* __restrict__ b1,
    const float* __restrict__ W2,     // [HID][9]
    const float* __restrict__ b2,
    float* __restrict__ Gp,           // [N][8] packed symmetric
    unsigned short* __restrict__ xwb, // [N][FOUT] bf16 bits
    const int* __restrict__ edges,
    int* __restrict__ cur,
    int* __restrict__ dst_r,          // [N][CAP]
    int N, int E) {
    __shared__ unsigned short xw_s[4][16][FOUT];
    __shared__ float h_lds[4][16][HID];
    __shared__ float M_lds[4][16][9];
    const int wid  = threadIdx.x >> 6;
    const int lane = threadIdx.x & 63;
    const int v0   = (blockIdx.x * 4 + wid) * 16;
    const int r    = lane & 15;
    const int hi   = lane >> 4;
    const int vr   = min(v0 + r, N - 1);

    // A fragments: 4 k-tiles of 32; lane holds feat[vr][kt*32 + hi*8 .. +8]
    bf16x8 a[4];
#pragma unroll
    for (int kt = 0; kt < 4; ++kt) {
        const float* src = feat + (size_t)vr * CIN + kt * 32 + hi * 8;
        const float4 f0 = ((const float4*)src)[0];
        const float4 f1 = ((const float4*)src)[1];
        bf16x8 t;
        t[0] = f2bf(f0.x); t[1] = f2bf(f0.y); t[2] = f2bf(f0.z); t[3] = f2bf(f0.w);
        t[4] = f2bf(f1.x); t[5] = f2bf(f1.y); t[6] = f2bf(f1.z); t[7] = f2bf(f1.w);
        a[kt] = t;
    }

    // xw: 8 column tiles of 16 -> stage in LDS
#pragma unroll
    for (int ct = 0; ct < 8; ++ct) {
        f32x4 acc = {0.f, 0.f, 0.f, 0.f};
#pragma unroll
        for (int kt = 0; kt < 4; ++kt) {
            const bf16x8 b = *((const bf16x8*)(WcT + (size_t)(ct * 16 + r) * CIN + kt * 32 + hi * 8));
            acc = __builtin_amdgcn_mfma_f32_16x16x32_bf16(a[kt], b, acc, 0, 0, 0);
        }
#pragma unroll
        for (int reg = 0; reg < 4; ++reg)
            xw_s[wid][hi * 4 + reg][ct * 16 + r] = (unsigned short)f2bf(acc[reg]);
    }

    // coalesced store: one 256B row per wave-wide dword store
#pragma unroll
    for (int row = 0; row < 16; ++row) {
        if (v0 + row < N) {
            const unsigned d = ((const unsigned*)xw_s[wid][row])[lane];
            ((unsigned*)(xwb + (size_t)(v0 + row) * FOUT))[lane] = d;
        }
    }

    // h: 2 column tiles of 16 over W1T
#pragma unroll
    for (int ct = 0; ct < 2; ++ct) {
        f32x4 acc = {0.f, 0.f, 0.f, 0.f};
#pragma unroll
        for (int kt = 0; kt < 4; ++kt) {
            const bf16x8 b = *((const bf16x8*)(W1T + (size_t)(ct * 16 + r) * CIN + kt * 32 + hi * 8));
            acc = __builtin_amdgcn_mfma_f32_16x16x32_bf16(a[kt], b, acc, 0, 0, 0);
        }
        const float bb = b1[ct * 16 + r];
#pragma unroll
        for (int reg = 0; reg < 4; ++reg)
            h_lds[wid][hi * 4 + reg][ct * 16 + r] = fmaxf(acc[reg] + bb, 0.f);
    }
    __syncthreads();

    // M = h @ W2 + b2  (16 verts x 9 outputs per wave)
    for (int idx = lane; idx < 144; idx += 64) {
        const int v = idx / 9, t = idx - v * 9;
        float m = b2[t];
#pragma unroll
        for (int k = 0; k < HID; ++k)
            m = fmaf(h_lds[wid][v][k], W2[k * 9 + t], m);
        M_lds[wid][v][t] = m;
    }
    __syncthreads();

    // Packed symmetric G: t in [0,6) -> (i,j) upper triangle
    for (int idx = lane; idx < 96; idx += 64) {
        const int v = idx / 6, t = idx - v * 6;
        const int i = (t >= 3) + (t >= 5);
        const int j = t - (t >= 3) * 2 - (t >= 5);
        float g = 0.f;
#pragma unroll
        for (int k = 0; k < 3; ++k)
            g += M_lds[wid][v][k * 3 + i] * M_lds[wid][v][k * 3 + j];
        if (v0 + v < N) Gp[(size_t)(v0 + v) * 8 + t] = g;
    }

    // ---- tail: bucket-scatter edges (no dependency on the vertex phase) ----
    const int gtid = blockIdx.x * 256 + threadIdx.x;
    const int gstride = gridDim.x * 256;
    for (int e = gtid; e < E; e += gstride) {
        const int s = edges[e];
        const int d = edges[E + e];
        const int rk = atomicAdd(&cur[s], 1);
        if (rk < CAP) dst_r[(size_t)s * CAP + rk] = d;
    }
}

// ---------------------------------------------------------------------------
// Aggregation: one wave per vertex. Phase 1: lanes 0..deg-1 each compute one
// edge weight (G/verts gathers are L2-resident). Phase 2: per-edge shfl
// broadcast of (dst, w), coalesced 256B xwb row gather, fma.
// ---------------------------------------------------------------------------
__global__ __launch_bounds__(256) void agg_kernel(const int* __restrict__ cur,
                                                  const int* __restrict__ dst_r,
                                                  const float* __restrict__ vertsP,
                                                  const float* __restrict__ Gp,
                                                  const unsigned short* __restrict__ xwb,
                                                  const float* __restrict__ bias,
                                                  float* __restrict__ out,
                                                  int N) {
    const int wid  = threadIdx.x >> 6;
    const int lane = threadIdx.x & 63;
    const int v = blockIdx.x * 4 + wid;
    if (v >= N) return;

    const int deg = min(cur[v], CAP);

    const float4 vs = ((const float4*)vertsP)[v];
    const float4 ga = ((const float4*)(Gp + (size_t)v * 8))[0];
    const float2 gb = ((const float2*)(Gp + (size_t)v * 8 + 4))[0];

    float ax = 0.f, ay = 0.f, wsum = 0.f;

    for (int base = 0; base < deg; base += 64) {
        const int cn = min(64, deg - base);

        int dval = 0; float wval = 0.f;
        if (lane < cn) {
            dval = dst_r[(size_t)v * CAP + base + lane];
            const float4 vd = ((const float4*)vertsP)[dval];
            const float4 ha = ((const float4*)(Gp + (size_t)dval * 8))[0];
            const float2 hb = ((const float2*)(Gp + (size_t)dval * 8 + 4))[0];
            const float t0 = vd.x - vs.x, t1 = vd.y - vs.y, t2 = vd.z - vs.z;
            const float g00 = ga.x + ha.x, g01 = ga.y + ha.y, g02 = ga.z + ha.z;
            const float g11 = ga.w + ha.w, g12 = gb.x + hb.x, g22 = gb.y + hb.y;
            const float q = 0.5f * (g00 * t0 * t0 + g11 * t1 * t1 + g22 * t2 * t2
                          + 2.f * (g01 * t0 * t1 + g02 * t0 * t2 + g12 * t1 * t2));
            wval = __expf(-q);
        }

        int k = 0;
        for (; k + 4 <= cn; k += 4) {
            const int   e0 = __shfl(dval, k,     64);
            const int   e1 = __shfl(dval, k + 1, 64);
            const int   e2 = __shfl(dval, k + 2, 64);
            const int   e3 = __shfl(dval, k + 3, 64);
            const float w0 = __shfl(wval, k,     64);
            const float w1 = __shfl(wval, k + 1, 64);
            const float w2 = __shfl(wval, k + 2, 64);
            const float w3 = __shfl(wval, k + 3, 64);
            const unsigned u0 = ((const unsigned*)(xwb + (size_t)e0 * FOUT))[lane];
            const unsigned u1 = ((const unsigned*)(xwb + (size_t)e1 * FOUT))[lane];
            const unsigned u2 = ((const unsigned*)(xwb + (size_t)e2 * FOUT))[lane];
            const unsigned u3 = ((const unsigned*)(xwb + (size_t)e3 * FOUT))[lane];
            ax = fmaf(w0, bfbits2f(u0 & 0xffffu), ax); ay = fmaf(w0, bfbits2f(u0 >> 16), ay);
            ax = fmaf(w1, bfbits2f(u1 & 0xffffu), ax); ay = fmaf(w1, bfbits2f(u1 >> 16), ay);
            ax = fmaf(w2, bfbits2f(u2 & 0xffffu), ax); ay = fmaf(w2, bfbits2f(u2 >> 16), ay);
            ax = fmaf(w3, bfbits2f(u3 & 0xffffu), ax); ay = fmaf(w3, bfbits2f(u3 >> 16), ay);
            wsum += (w0 + w1) + (w2 + w3);
        }
        for (; k < cn; ++k) {
            const int   e0 = __shfl(dval, k, 64);
            const float w0 = __shfl(wval, k, 64);
            const unsigned u0 = ((const unsigned*)(xwb + (size_t)e0 * FOUT))[lane];
            ax = fmaf(w0, bfbits2f(u0 & 0xffffu), ax);
            ay = fmaf(w0, bfbits2f(u0 >> 16), ay);
            wsum += w0;
        }
    }

    const float inv = 1.f / (wsum + EPSV);
    const float2 b = ((const float2*)bias)[lane];
    float2 o;
    o.x = ax * inv + b.x;
    o.y = ay * inv + b.y;
    ((float2*)(out + (size_t)v * FOUT))[lane] = o;
}

extern "C" void kernel_launch(void* const* d_in, const int* in_sizes, int n_in,
                              void* d_out, int out_size, void* d_ws, size_t ws_size,
                              hipStream_t stream) {
    const float* feat  = (const float*)d_in[0];
    const float* verts = (const float*)d_in[1];
    const int*   edges = (const int*)d_in[2];
    // d_in[3] = faces (unused)
    const float* W1    = (const float*)d_in[4];
    const float* b1    = (const float*)d_in[5];
    const float* W2    = (const float*)d_in[6];
    const float* b2    = (const float*)d_in[7];
    const float* Wc    = (const float*)d_in[8];
    const float* bias  = (const float*)d_in[9];

    const int N = in_sizes[0] / CIN;
    const int E = in_sizes[2] / 2;

    // workspace layout (256B-aligned chunks)
    char* p = (char*)d_ws;
    auto alloc = [&](size_t bytes) {
        char* r = p;
        p += (bytes + 255) & ~(size_t)255;
        return r;
    };
    short*          WcT    = (short*)alloc((size_t)CIN * FOUT * sizeof(short));
    short*          W1T    = (short*)alloc((size_t)HID * CIN * sizeof(short));
    unsigned short* xwb    = (unsigned short*)alloc((size_t)N * FOUT * sizeof(short));
    float*          Gp     = (float*)alloc((size_t)N * 8 * sizeof(float));
    float*          vertsP = (float*)alloc((size_t)N * 4 * sizeof(float));
    int*            dst_r  = (int*)alloc((size_t)N * CAP * sizeof(int));
    int*            cur    = (int*)alloc((size_t)N * sizeof(int));
    float*          out    = (float*)d_out;

    const int prep_n = (N > CIN * FOUT) ? N : CIN * FOUT;
    prep_kernel<<<(prep_n + 255) / 256, 256, 0, stream>>>(Wc, W1, verts, WcT, W1T, vertsP, cur, N);

    const int nwaves = (N + 15) / 16;
    vertex_mfma<<<(nwaves + 3) / 4, 256, 0, stream>>>(feat, WcT, W1T, b1, W2, b2, Gp, xwb,
                                                      edges, cur, dst_r, N, E);

    agg_kernel<<<(N + 3) / 4, 256, 0, stream>>>(cur, dst_r, vertsP, Gp, xwb, bias, out, N);
}